// Round 6
// baseline (321.586 us; speedup 1.0000x reference)
//
#include <hip/hip_runtime.h>
#include <hip/hip_bf16.h>

typedef __attribute__((ext_vector_type(4))) float f32x4;
typedef __attribute__((ext_vector_type(2))) float f32x2;
typedef __attribute__((ext_vector_type(8))) short bf16x8;
typedef __attribute__((ext_vector_type(4))) short s16x4;

#define BA 48
#define BB 48
#define SS 96
#define DIN 768
#define HH 256

static __device__ __forceinline__ short f2bf(float f) {
    __hip_bfloat16 h = __float2bfloat16(f);
    return *reinterpret_cast<short*>(&h);
}

static __device__ __forceinline__ f32x4 mfma16(bf16x8 a, bf16x8 b, f32x4 c) {
    return __builtin_amdgcn_mfma_f32_16x16x32_bf16(a, b, c, 0, 0, 0);
}

// ---------------------------------------------------------------------------
// Kernel 0: tiled transpose+convert: W[768][256] f32 -> Wt[3][256][768] bf16.
// 64x64 tiles via LDS; coalesced loads AND 128B-contiguous stores
// (old version: 2B stores 1536B apart -> heavy partial-line write amp).
// grid (12, 4, 3), 256 thr.
// ---------------------------------------------------------------------------
__global__ __launch_bounds__(256) void wt_kernel(
    const float* __restrict__ Wq, const float* __restrict__ Wk,
    const float* __restrict__ Wv, short* __restrict__ wt) {
    __shared__ float tile[64][65];
    int k0 = blockIdx.x * 64, n0 = blockIdx.y * 64, mat = blockIdx.z;
    const float* W = (mat == 0) ? Wq : (mat == 1) ? Wk : Wv;
    int t = threadIdx.x;
#pragma unroll
    for (int j = 0; j < 16; ++j) {
        int kk = j * 4 + (t >> 6);
        int nn = t & 63;
        tile[kk][nn] = W[(size_t)(k0 + kk) * HH + n0 + nn];
    }
    __syncthreads();
#pragma unroll
    for (int j = 0; j < 4; ++j) {
        int nn = j * 16 + (t >> 4);
        int kk = (t & 15) * 4;
        s16x4 pk;
#pragma unroll
        for (int i = 0; i < 4; ++i) pk[i] = f2bf(tile[kk + i][nn]);
        *reinterpret_cast<s16x4*>(&wt[(size_t)(mat * HH + n0 + nn) * DIN + k0 + kk]) = pk;
    }
}

// ---------------------------------------------------------------------------
// Kernel 1: QKV projection, split 4x along N for occupancy.
// grid (48, 3, 4): batch, mat(0=q,1=k,2=v), 64-col tile. 384 thr = 6 waves.
// ---------------------------------------------------------------------------
__global__ __launch_bounds__(384) void qkv_kernel(
    const float* __restrict__ Xa, const float* __restrict__ Xb,
    const float* __restrict__ bq, const float* __restrict__ bk, const float* __restrict__ bv,
    const short* __restrict__ wt,
    float* __restrict__ q_ws, float* __restrict__ k_ws, short* __restrict__ vt_ws) {
    __shared__ short vtile[64][104];

    int bb = blockIdx.x;
    int mat = blockIdx.y;
    int c0 = blockIdx.z * 64;
    int tid = threadIdx.x;
    int wave = tid >> 6, lane = tid & 63;
    int c = lane & 15, g = lane >> 4;

    const float* X = ((mat == 0) ? Xa : Xb) + bb * SS * DIN;
    const short* Wt = wt + mat * HH * DIN;
    const float* bias = (mat == 0) ? bq : (mat == 1) ? bk : bv;

    const f32x4 z4 = {0.f, 0.f, 0.f, 0.f};
    f32x4 acc[4];
#pragma unroll
    for (int n = 0; n < 4; ++n) acc[n] = z4;

    const float* ap = X + (16 * wave + c) * DIN + g * 8;
    const short* bp = Wt + (c0 + c) * DIN + g * 8;
    for (int kk = 0; kk < DIN; kk += 32) {
        f32x4 a0 = *reinterpret_cast<const f32x4*>(ap + kk);
        f32x4 a1 = *reinterpret_cast<const f32x4*>(ap + kk + 4);
        bf16x8 af;
        af[0] = f2bf(a0[0]); af[1] = f2bf(a0[1]); af[2] = f2bf(a0[2]); af[3] = f2bf(a0[3]);
        af[4] = f2bf(a1[0]); af[5] = f2bf(a1[1]); af[6] = f2bf(a1[2]); af[7] = f2bf(a1[3]);
#pragma unroll
        for (int n = 0; n < 4; ++n) {
            bf16x8 bf = *reinterpret_cast<const bf16x8*>(bp + n * 16 * DIN + kk);
            acc[n] = mfma16(af, bf, acc[n]);
        }
    }
#pragma unroll
    for (int n = 0; n < 4; ++n) {
        float bv_ = bias[c0 + n * 16 + c];
#pragma unroll
        for (int r = 0; r < 4; ++r) acc[n][r] += bv_;
    }

    if (mat < 2) {
        float* dst = (mat == 0) ? q_ws : k_ws;
#pragma unroll
        for (int n = 0; n < 4; ++n)
#pragma unroll
            for (int r = 0; r < 4; ++r)
                dst[(bb * SS + 16 * wave + 4 * g + r) * HH + c0 + n * 16 + c] = acc[n][r];
    } else {
#pragma unroll
        for (int n = 0; n < 4; ++n)
#pragma unroll
            for (int r = 0; r < 4; ++r)
                vtile[n * 16 + c][16 * wave + 4 * g + r] = f2bf(acc[n][r]);
        __syncthreads();
#pragma unroll
        for (int t2 = 0; t2 < 2; ++t2) {
            int t = tid + t2 * 384;
            int d = t / 12, ch = t % 12;
            bf16x8 pk = *reinterpret_cast<const bf16x8*>(&vtile[d][ch * 8]);
            *reinterpret_cast<bf16x8*>(vt_ws + ((size_t)(bb * HH) + c0 + d) * SS + ch * 8) = pk;
        }
    }
}

// ---------------------------------------------------------------------------
// Kernel 2: row L2 norms for q,k -> qn,kn bf16. One wave per row.
// ---------------------------------------------------------------------------
__global__ __launch_bounds__(256) void norm_kernel(
    const float* __restrict__ q_ws, const float* __restrict__ k_ws,
    short* __restrict__ qn_ws, short* __restrict__ kn_ws) {
    int row = blockIdx.x * 4 + (threadIdx.x >> 6);
    int lane = threadIdx.x & 63;
    int isq = (row < 4608);
    const float* src = isq ? q_ws : k_ws;
    short* dst = isq ? qn_ws : kn_ws;
    int r = isq ? row : row - 4608;

    f32x4 v = *reinterpret_cast<const f32x4*>(src + (size_t)r * HH + lane * 4);
    float s = v[0] * v[0] + v[1] * v[1] + v[2] * v[2] + v[3] * v[3];
#pragma unroll
    for (int m = 1; m < 64; m <<= 1) s += __shfl_xor(s, m);
    float inv = 1.0f / fmaxf(sqrtf(s), 1e-8f);
    s16x4 o;
#pragma unroll
    for (int j = 0; j < 4; ++j) o[j] = f2bf(v[j] * inv);
    *reinterpret_cast<s16x4*>(dst + (size_t)r * HH + lane * 4) = o;
}

// ---------------------------------------------------------------------------
// Kernel 3a: sink_kernel — per (a,b): QK^T + register Sinkhorn + row-L2,
// write T bf16 [a_local][b][96][96]. 384 thr = 6 waves, ALL waves work.
// LDS 2.7KB, high occupancy (~5 blocks/CU) hides the barrier chain.
// ---------------------------------------------------------------------------
__global__ __launch_bounds__(384) void sink_kernel(
    const short* __restrict__ qn_ws, const short* __restrict__ kn_ws,
    short* __restrict__ t_ws, int a_off) {
    __shared__ float colpart[6][SS];
    __shared__ float cinv[SS];

    int b = blockIdx.x, al = blockIdx.y;
    int a = al + a_off;
    int tid = threadIdx.x;
    int rt = tid >> 6, lane = tid & 63;
    int c = lane & 15, g = lane >> 4;

    const f32x4 z4 = {0.f, 0.f, 0.f, 0.f};
    f32x4 K[6];
#pragma unroll
    for (int f = 0; f < 6; ++f) K[f] = z4;

    // swapped QK^T: lane owns C[i=16rt+c][j=16f+4g+r]
    const short* qp = qn_ws + ((size_t)(a * SS) + 16 * rt + c) * HH + g * 8;
    const short* kp = kn_ws + ((size_t)(b * SS) + c) * HH + g * 8;
#pragma unroll
    for (int kk = 0; kk < HH; kk += 32) {
        bf16x8 qf = *reinterpret_cast<const bf16x8*>(qp + kk);
#pragma unroll
        for (int f = 0; f < 6; ++f) {
            bf16x8 kf = *reinterpret_cast<const bf16x8*>(kp + f * 16 * HH + kk);
            K[f] = mfma16(kf, qf, K[f]);
        }
    }
#pragma unroll
    for (int f = 0; f < 6; ++f)
#pragma unroll
        for (int r = 0; r < 4; ++r)
            K[f][r] = exp2f(K[f][r] * 14.4269504088896341f);  // exp(10*C)

    for (int it = 0; it < 5; ++it) {
        float rs = 0.f;
#pragma unroll
        for (int f = 0; f < 6; ++f) rs += K[f][0] + K[f][1] + K[f][2] + K[f][3];
        rs += __shfl_xor(rs, 16);
        rs += __shfl_xor(rs, 32);
        float rinv = 1.0f / rs;
#pragma unroll
        for (int f = 0; f < 6; ++f)
#pragma unroll
            for (int r = 0; r < 4; ++r) K[f][r] *= rinv;

#pragma unroll
        for (int f = 0; f < 6; ++f) {
            f32x4 cs = K[f];
#pragma unroll
            for (int m = 1; m < 16; m <<= 1)
#pragma unroll
                for (int r = 0; r < 4; ++r) cs[r] += __shfl_xor(cs[r], m);
            if (c == 0)
                *reinterpret_cast<f32x4*>(&colpart[rt][16 * f + 4 * g]) = cs;
        }
        __syncthreads();
        if (tid < SS) {
            float s = colpart[0][tid] + colpart[1][tid] + colpart[2][tid] +
                      colpart[3][tid] + colpart[4][tid] + colpart[5][tid];
            cinv[tid] = 1.0f / s;
        }
        __syncthreads();
#pragma unroll
        for (int f = 0; f < 6; ++f) {
            f32x4 ci = *reinterpret_cast<const f32x4*>(&cinv[16 * f + 4 * g]);
#pragma unroll
            for (int r = 0; r < 4; ++r) K[f][r] *= ci[r];
        }
    }

    float ss = 0.f;
#pragma unroll
    for (int f = 0; f < 6; ++f)
#pragma unroll
        for (int r = 0; r < 4; ++r) ss += K[f][r] * K[f][r];
    ss += __shfl_xor(ss, 16);
    ss += __shfl_xor(ss, 32);
    float linv = 1.0f / fmaxf(sqrtf(ss), 1e-12f);

    short* tp = t_ws + ((size_t)(al * BB + b)) * SS * SS + (16 * rt + c) * SS;
#pragma unroll
    for (int f = 0; f < 6; ++f) {
        s16x4 pk;
#pragma unroll
        for (int r = 0; r < 4; ++r) pk[r] = f2bf(K[f][r] * linv);
        *reinterpret_cast<s16x4*>(tp + 16 * f + 4 * g) = pk;
    }
}

// ---------------------------------------------------------------------------
// Kernel 3b: pv_kernel — per (a,b): T@v + q residual -> LayerNorm -> out.
// 768 thr, 12 waves (rt = w%6, h = w/6), ONE barrier. T fragments loaded
// straight from global (16B vector loads). Streaming-friendly.
// ---------------------------------------------------------------------------
__global__ __launch_bounds__(768, 6) void pv_kernel(
    const short* __restrict__ t_ws, const short* __restrict__ vt_ws,
    const float* __restrict__ q_ws,
    const float* __restrict__ ln_g, const float* __restrict__ ln_b,
    float* __restrict__ out, int a_off) {
    __shared__ float stats[2][2][SS];      //  1536 B [half][s1|s2][row]
    __shared__ float etile[12][4][136];    // 26112 B per-wave transpose tiles

    int b = blockIdx.x, al = blockIdx.y;
    int a = al + a_off;
    int tid = threadIdx.x;
    int wave = tid >> 6, lane = tid & 63;
    int rt = wave % 6, h = wave / 6;
    int c = lane & 15, g = lane >> 4;

    const f32x4 z4 = {0.f, 0.f, 0.f, 0.f};
    f32x4 acc[8];
#pragma unroll
    for (int n = 0; n < 8; ++n) acc[n] = z4;

    const short* tp = t_ws + ((size_t)(al * BB + b)) * SS * SS + (16 * rt + c) * SS + g * 8;
    const short* vp = vt_ws + ((size_t)(b * HH) + 128 * h + c) * SS + g * 8;
#pragma unroll
    for (int ks = 0; ks < 3; ++ks) {
        bf16x8 af = *reinterpret_cast<const bf16x8*>(tp + ks * 32);
#pragma unroll
        for (int n = 0; n < 8; ++n) {
            bf16x8 bf = *reinterpret_cast<const bf16x8*>(vp + n * 16 * SS + ks * 32);
            acc[n] = mfma16(af, bf, acc[n]);
        }
    }

    // + q residual, LN stats (cross-half via LDS)
    const float* qa = q_ws + (size_t)a * SS * HH + 128 * h;
    int r0 = 16 * rt + 4 * g;
    float s1[4] = {0.f, 0.f, 0.f, 0.f};
    float s2[4] = {0.f, 0.f, 0.f, 0.f};
#pragma unroll
    for (int n = 0; n < 8; ++n)
#pragma unroll
        for (int r = 0; r < 4; ++r) {
            float x = acc[n][r] + qa[(r0 + r) * HH + n * 16 + c];
            acc[n][r] = x;
            s1[r] += x;
            s2[r] += x * x;
        }
#pragma unroll
    for (int m = 1; m < 16; m <<= 1)
#pragma unroll
        for (int r = 0; r < 4; ++r) {
            s1[r] += __shfl_xor(s1[r], m);
            s2[r] += __shfl_xor(s2[r], m);
        }
    if (c == 0) {
#pragma unroll
        for (int r = 0; r < 4; ++r) {
            stats[h][0][r0 + r] = s1[r];
            stats[h][1][r0 + r] = s2[r];
        }
    }
    __syncthreads();
    float mean[4], inv[4];
#pragma unroll
    for (int r = 0; r < 4; ++r) {
        float t1 = stats[0][0][r0 + r] + stats[1][0][r0 + r];
        float t2 = stats[0][1][r0 + r] + stats[1][1][r0 + r];
        mean[r] = t1 * (1.0f / 256.0f);
        float var = t2 * (1.0f / 256.0f) - mean[r] * mean[r];
        inv[r] = rsqrtf(var + 1e-5f);
    }

    // per-wave LDS transpose -> full-line f32x2 stores
    f32x2 g2 = *reinterpret_cast<const f32x2*>(ln_g + 128 * h + 2 * lane);
    f32x2 b2 = *reinterpret_cast<const f32x2*>(ln_b + 128 * h + 2 * lane);
    float* ob = out + ((size_t)(a * BB + b)) * SS * HH + 128 * h;
#pragma unroll
    for (int r = 0; r < 4; ++r) {
#pragma unroll
        for (int n = 0; n < 8; ++n)
            etile[wave][g][n * 16 + c] = (acc[n][r] - mean[r]) * inv[r];
        // wave-private tile: in-wave LDS ordering (lgkmcnt), no barrier needed
#pragma unroll
        for (int t = 0; t < 4; ++t) {
            f32x2 x2 = *reinterpret_cast<const f32x2*>(&etile[wave][t][2 * lane]);
            *reinterpret_cast<f32x2*>(ob + (size_t)(16 * rt + 4 * t + r) * HH + 2 * lane) =
                x2 * g2 + b2;
        }
    }
}

// ---------------------------------------------------------------------------
extern "C" void kernel_launch(void* const* d_in, const int* in_sizes, int n_in,
                              void* d_out, int out_size, void* d_ws, size_t ws_size,
                              hipStream_t stream) {
    const float* Xa = (const float*)d_in[0];
    const float* Xb = (const float*)d_in[1];
    const float* Wq = (const float*)d_in[2];
    const float* bq = (const float*)d_in[3];
    const float* Wk = (const float*)d_in[4];
    const float* bk = (const float*)d_in[5];
    const float* Wv = (const float*)d_in[6];
    const float* bv = (const float*)d_in[7];
    const float* ln_g = (const float*)d_in[8];
    const float* ln_b = (const float*)d_in[9];
    float* out = (float*)d_out;

    char* ws = (char*)d_ws;
    short* wt    = (short*)(ws);               // 1,179,648 B
    float* q_ws  = (float*)(ws + 1179648);     // 4,718,592 B
    float* k_ws  = (float*)(ws + 5898240);     // 4,718,592 B (dead after norm)
    short* qn_ws = (short*)(ws + 10616832);    // 2,359,296 B
    short* kn_ws = (short*)(ws + 12976128);    // 2,359,296 B
    short* vt_ws = (short*)(ws + 15335424);    // 2,359,296 B (end 17,694,720)

    // T buffer: up to 48x48x96x96 bf16 = 42,467,328 B; chunk if ws is small.
    const size_t t_full = (size_t)BA * BB * SS * SS * 2;
    size_t t_off = 17694720;
    size_t avail = (ws_size > t_off) ? ws_size - t_off : 0;
    int nch;
    if (avail >= t_full) nch = 1;
    else if (avail >= t_full / 2) nch = 2;
    else if (avail >= t_full / 4) nch = 4;
    else if (avail >= t_full / 8) nch = 8;
    else { nch = 16; t_off = 5898240; }  // overlay dead k_ws (needs 2.66 MB)
    short* t_ws = (short*)(ws + t_off);
    int apc = BA / nch;

    wt_kernel<<<dim3(12, 4, 3), dim3(256), 0, stream>>>(Wq, Wk, Wv, wt);
    qkv_kernel<<<dim3(BA, 3, 4), dim3(384), 0, stream>>>(Xa, Xb, bq, bk, bv, wt,
                                                         q_ws, k_ws, vt_ws);
    norm_kernel<<<dim3(2304), dim3(256), 0, stream>>>(q_ws, k_ws, qn_ws, kn_ws);
    for (int ch = 0; ch < nch; ++ch) {
        sink_kernel<<<dim3(BB, apc), dim3(384), 0, stream>>>(qn_ws, kn_ws, t_ws, ch * apc);
        pv_kernel<<<dim3(BB, apc), dim3(768), 0, stream>>>(t_ws, vt_ws, q_ws,
                                                           ln_g, ln_b, out, ch * apc);
    }
}

// Round 7
// 252.501 us; speedup vs baseline: 1.2736x; 1.2736x over previous
//
#include <hip/hip_runtime.h>
#include <hip/hip_bf16.h>

typedef __attribute__((ext_vector_type(4))) float f32x4;
typedef __attribute__((ext_vector_type(2))) float f32x2;
typedef __attribute__((ext_vector_type(8))) short bf16x8;
typedef __attribute__((ext_vector_type(4))) short s16x4;

#define BA 48
#define BB 48
#define SS 96
#define DIN 768
#define HH 256

static __device__ __forceinline__ short f2bf(float f) {
    __hip_bfloat16 h = __float2bfloat16(f);
    return *reinterpret_cast<short*>(&h);
}

static __device__ __forceinline__ f32x4 mfma16(bf16x8 a, bf16x8 b, f32x4 c) {
    return __builtin_amdgcn_mfma_f32_16x16x32_bf16(a, b, c, 0, 0, 0);
}

// ---------------------------------------------------------------------------
// Kernel 0: tiled transpose+convert: W[768][256] f32 -> Wt[3][256][768] bf16.
// ---------------------------------------------------------------------------
__global__ __launch_bounds__(256) void wt_kernel(
    const float* __restrict__ Wq, const float* __restrict__ Wk,
    const float* __restrict__ Wv, short* __restrict__ wt) {
    __shared__ float tile[64][65];
    int k0 = blockIdx.x * 64, n0 = blockIdx.y * 64, mat = blockIdx.z;
    const float* W = (mat == 0) ? Wq : (mat == 1) ? Wk : Wv;
    int t = threadIdx.x;
#pragma unroll
    for (int j = 0; j < 16; ++j) {
        int kk = j * 4 + (t >> 6);
        int nn = t & 63;
        tile[kk][nn] = W[(size_t)(k0 + kk) * HH + n0 + nn];
    }
    __syncthreads();
#pragma unroll
    for (int j = 0; j < 4; ++j) {
        int nn = j * 16 + (t >> 4);
        int kk = (t & 15) * 4;
        s16x4 pk;
#pragma unroll
        for (int i = 0; i < 4; ++i) pk[i] = f2bf(tile[kk + i][nn]);
        *reinterpret_cast<s16x4*>(&wt[(size_t)(mat * HH + n0 + nn) * DIN + k0 + kk]) = pk;
    }
}

// ---------------------------------------------------------------------------
// Kernel 1: QKV projection, split 4x along N for occupancy.
// grid (48, 3, 4): batch, mat(0=q,1=k,2=v), 64-col tile. 384 thr = 6 waves.
// ---------------------------------------------------------------------------
__global__ __launch_bounds__(384) void qkv_kernel(
    const float* __restrict__ Xa, const float* __restrict__ Xb,
    const float* __restrict__ bq, const float* __restrict__ bk, const float* __restrict__ bv,
    const short* __restrict__ wt,
    float* __restrict__ q_ws, float* __restrict__ k_ws, short* __restrict__ vt_ws) {
    __shared__ short vtile[64][104];

    int bb = blockIdx.x;
    int mat = blockIdx.y;
    int c0 = blockIdx.z * 64;
    int tid = threadIdx.x;
    int wave = tid >> 6, lane = tid & 63;
    int c = lane & 15, g = lane >> 4;

    const float* X = ((mat == 0) ? Xa : Xb) + bb * SS * DIN;
    const short* Wt = wt + mat * HH * DIN;
    const float* bias = (mat == 0) ? bq : (mat == 1) ? bk : bv;

    const f32x4 z4 = {0.f, 0.f, 0.f, 0.f};
    f32x4 acc[4];
#pragma unroll
    for (int n = 0; n < 4; ++n) acc[n] = z4;

    const float* ap = X + (16 * wave + c) * DIN + g * 8;
    const short* bp = Wt + (c0 + c) * DIN + g * 8;
    for (int kk = 0; kk < DIN; kk += 32) {
        f32x4 a0 = *reinterpret_cast<const f32x4*>(ap + kk);
        f32x4 a1 = *reinterpret_cast<const f32x4*>(ap + kk + 4);
        bf16x8 af;
        af[0] = f2bf(a0[0]); af[1] = f2bf(a0[1]); af[2] = f2bf(a0[2]); af[3] = f2bf(a0[3]);
        af[4] = f2bf(a1[0]); af[5] = f2bf(a1[1]); af[6] = f2bf(a1[2]); af[7] = f2bf(a1[3]);
#pragma unroll
        for (int n = 0; n < 4; ++n) {
            bf16x8 bf = *reinterpret_cast<const bf16x8*>(bp + n * 16 * DIN + kk);
            acc[n] = mfma16(af, bf, acc[n]);
        }
    }
#pragma unroll
    for (int n = 0; n < 4; ++n) {
        float bv_ = bias[c0 + n * 16 + c];
#pragma unroll
        for (int r = 0; r < 4; ++r) acc[n][r] += bv_;
    }

    if (mat < 2) {
        float* dst = (mat == 0) ? q_ws : k_ws;
#pragma unroll
        for (int n = 0; n < 4; ++n)
#pragma unroll
            for (int r = 0; r < 4; ++r)
                dst[(bb * SS + 16 * wave + 4 * g + r) * HH + c0 + n * 16 + c] = acc[n][r];
    } else {
#pragma unroll
        for (int n = 0; n < 4; ++n)
#pragma unroll
            for (int r = 0; r < 4; ++r)
                vtile[n * 16 + c][16 * wave + 4 * g + r] = f2bf(acc[n][r]);
        __syncthreads();
#pragma unroll
        for (int t2 = 0; t2 < 2; ++t2) {
            int t = tid + t2 * 384;
            int d = t / 12, ch = t % 12;
            bf16x8 pk = *reinterpret_cast<const bf16x8*>(&vtile[d][ch * 8]);
            *reinterpret_cast<bf16x8*>(vt_ws + ((size_t)(bb * HH) + c0 + d) * SS + ch * 8) = pk;
        }
    }
}

// ---------------------------------------------------------------------------
// Kernel 2: row L2 norms for q,k -> qn,kn bf16. One wave per row.
// ---------------------------------------------------------------------------
__global__ __launch_bounds__(256) void norm_kernel(
    const float* __restrict__ q_ws, const float* __restrict__ k_ws,
    short* __restrict__ qn_ws, short* __restrict__ kn_ws) {
    int row = blockIdx.x * 4 + (threadIdx.x >> 6);
    int lane = threadIdx.x & 63;
    int isq = (row < 4608);
    const float* src = isq ? q_ws : k_ws;
    short* dst = isq ? qn_ws : kn_ws;
    int r = isq ? row : row - 4608;

    f32x4 v = *reinterpret_cast<const f32x4*>(src + (size_t)r * HH + lane * 4);
    float s = v[0] * v[0] + v[1] * v[1] + v[2] * v[2] + v[3] * v[3];
#pragma unroll
    for (int m = 1; m < 64; m <<= 1) s += __shfl_xor(s, m);
    float inv = 1.0f / fmaxf(sqrtf(s), 1e-8f);
    s16x4 o;
#pragma unroll
    for (int j = 0; j < 4; ++j) o[j] = f2bf(v[j] * inv);
    *reinterpret_cast<s16x4*>(dst + (size_t)r * HH + lane * 4) = o;
}

// ---------------------------------------------------------------------------
// Kernel 3a: sink_kernel — ONE WAVE PER (a,b) PAIR, whole 96x96 kernel matrix
// register-resident: K[ti][tj][r] = C[i=16ti+c][j=16tj+4g+r] (144 f32/lane).
// Row reduce: 24 local + shfl_xor(16,32). Col reduce: 6 reg adds +
// shfl_xor(1,2,4,8). ZERO barriers, ZERO LDS. 256 thr = 4 pairs/block.
// __launch_bounds__(256,2): 256-VGPR cap, 2 waves/SIMD, 8 pairs/CU in flight.
// ---------------------------------------------------------------------------
__global__ __launch_bounds__(256, 2) void sink_kernel(
    const short* __restrict__ qn_ws, const short* __restrict__ kn_ws,
    short* __restrict__ t_ws, int a_off) {
    int wave = threadIdx.x >> 6, lane = threadIdx.x & 63;
    int c = lane & 15, g = lane >> 4;
    int b = blockIdx.x * 4 + wave;
    int al = blockIdx.y;
    int a = al + a_off;

    const short* qbase = qn_ws + (size_t)(a * SS) * HH + c * HH + g * 8;
    const short* kbase = kn_ws + (size_t)(b * SS) * HH + c * HH + g * 8;

    const f32x4 z4 = {0.f, 0.f, 0.f, 0.f};
    f32x4 K[6][6];
#pragma unroll
    for (int ti = 0; ti < 6; ++ti)
#pragma unroll
        for (int tj = 0; tj < 6; ++tj) K[ti][tj] = z4;

    // ---- QK^T: 36 tiles, 8 k-steps. qf[ti] reused across tj. ----
#pragma unroll
    for (int kk = 0; kk < 8; ++kk) {
        bf16x8 qf[6];
#pragma unroll
        for (int ti = 0; ti < 6; ++ti)
            qf[ti] = *reinterpret_cast<const bf16x8*>(qbase + ti * 16 * HH + kk * 32);
#pragma unroll
        for (int tj = 0; tj < 6; ++tj) {
            bf16x8 kf = *reinterpret_cast<const bf16x8*>(kbase + tj * 16 * HH + kk * 32);
#pragma unroll
            for (int ti = 0; ti < 6; ++ti)
                K[ti][tj] = mfma16(kf, qf[ti], K[ti][tj]);
        }
    }

    // ---- exp(C/eps) = exp2(C * 10*log2(e)) ----
#pragma unroll
    for (int ti = 0; ti < 6; ++ti)
#pragma unroll
        for (int tj = 0; tj < 6; ++tj)
#pragma unroll
            for (int r = 0; r < 4; ++r)
                K[ti][tj][r] = exp2f(K[ti][tj][r] * 14.4269504088896341f);

    // ---- Sinkhorn: 5 x (row normalize, col normalize). All in-wave. ----
#pragma unroll 1
    for (int it = 0; it < 5; ++it) {
        // rows: i = 16ti + c. Local 24-sum, then reduce over g (xor 16,32).
#pragma unroll
        for (int ti = 0; ti < 6; ++ti) {
            float rs = 0.f;
#pragma unroll
            for (int tj = 0; tj < 6; ++tj)
                rs += K[ti][tj][0] + K[ti][tj][1] + K[ti][tj][2] + K[ti][tj][3];
            rs += __shfl_xor(rs, 16);
            rs += __shfl_xor(rs, 32);
            float rinv = 1.0f / rs;
#pragma unroll
            for (int tj = 0; tj < 6; ++tj)
#pragma unroll
                for (int r = 0; r < 4; ++r) K[ti][tj][r] *= rinv;
        }
        // cols: j = 16tj + 4g + r. 6 reg adds, then reduce over c (xor 1..8).
        f32x4 cs[6];
#pragma unroll
        for (int tj = 0; tj < 6; ++tj) {
            cs[tj] = K[0][tj];
#pragma unroll
            for (int ti = 1; ti < 6; ++ti)
#pragma unroll
                for (int r = 0; r < 4; ++r) cs[tj][r] += K[ti][tj][r];
        }
#pragma unroll
        for (int m = 1; m < 16; m <<= 1)
#pragma unroll
            for (int tj = 0; tj < 6; ++tj)
#pragma unroll
                for (int r = 0; r < 4; ++r) cs[tj][r] += __shfl_xor(cs[tj][r], m);
#pragma unroll
        for (int tj = 0; tj < 6; ++tj) {
#pragma unroll
            for (int r = 0; r < 4; ++r) cs[tj][r] = 1.0f / cs[tj][r];
#pragma unroll
            for (int ti = 0; ti < 6; ++ti)
#pragma unroll
                for (int r = 0; r < 4; ++r) K[ti][tj][r] *= cs[tj][r];
        }
    }

    // ---- final row L2 normalize + bf16 store (8B chunks, 4 g-lanes/32B) ----
    short* tp = t_ws + (size_t)(al * BB + b) * SS * SS;
#pragma unroll
    for (int ti = 0; ti < 6; ++ti) {
        float ss = 0.f;
#pragma unroll
        for (int tj = 0; tj < 6; ++tj)
#pragma unroll
            for (int r = 0; r < 4; ++r) ss += K[ti][tj][r] * K[ti][tj][r];
        ss += __shfl_xor(ss, 16);
        ss += __shfl_xor(ss, 32);
        float linv = 1.0f / fmaxf(sqrtf(ss), 1e-12f);
#pragma unroll
        for (int tj = 0; tj < 6; ++tj) {
            s16x4 pk;
#pragma unroll
            for (int r = 0; r < 4; ++r) pk[r] = f2bf(K[ti][tj][r] * linv);
            *reinterpret_cast<s16x4*>(tp + (16 * ti + c) * SS + 16 * tj + 4 * g) = pk;
        }
    }
}

// ---------------------------------------------------------------------------
// Kernel 3b: pv_kernel — per (a,b): T@v + q residual -> LayerNorm -> out.
// 768 thr, 12 waves (rt = w%6, h = w/6), ONE barrier.
// ---------------------------------------------------------------------------
__global__ __launch_bounds__(768, 6) void pv_kernel(
    const short* __restrict__ t_ws, const short* __restrict__ vt_ws,
    const float* __restrict__ q_ws,
    const float* __restrict__ ln_g, const float* __restrict__ ln_b,
    float* __restrict__ out, int a_off) {
    __shared__ float stats[2][2][SS];      //  1536 B [half][s1|s2][row]
    __shared__ float etile[12][4][136];    // 26112 B per-wave transpose tiles

    int b = blockIdx.x, al = blockIdx.y;
    int a = al + a_off;
    int tid = threadIdx.x;
    int wave = tid >> 6, lane = tid & 63;
    int rt = wave % 6, h = wave / 6;
    int c = lane & 15, g = lane >> 4;

    const f32x4 z4 = {0.f, 0.f, 0.f, 0.f};
    f32x4 acc[8];
#pragma unroll
    for (int n = 0; n < 8; ++n) acc[n] = z4;

    const short* tp = t_ws + ((size_t)(al * BB + b)) * SS * SS + (16 * rt + c) * SS + g * 8;
    const short* vp = vt_ws + ((size_t)(b * HH) + 128 * h + c) * SS + g * 8;
#pragma unroll
    for (int ks = 0; ks < 3; ++ks) {
        bf16x8 af = *reinterpret_cast<const bf16x8*>(tp + ks * 32);
#pragma unroll
        for (int n = 0; n < 8; ++n) {
            bf16x8 bf = *reinterpret_cast<const bf16x8*>(vp + n * 16 * SS + ks * 32);
            acc[n] = mfma16(af, bf, acc[n]);
        }
    }

    // + q residual, LN stats (cross-half via LDS)
    const float* qa = q_ws + (size_t)a * SS * HH + 128 * h;
    int r0 = 16 * rt + 4 * g;
    float s1[4] = {0.f, 0.f, 0.f, 0.f};
    float s2[4] = {0.f, 0.f, 0.f, 0.f};
#pragma unroll
    for (int n = 0; n < 8; ++n)
#pragma unroll
        for (int r = 0; r < 4; ++r) {
            float x = acc[n][r] + qa[(r0 + r) * HH + n * 16 + c];
            acc[n][r] = x;
            s1[r] += x;
            s2[r] += x * x;
        }
#pragma unroll
    for (int m = 1; m < 16; m <<= 1)
#pragma unroll
        for (int r = 0; r < 4; ++r) {
            s1[r] += __shfl_xor(s1[r], m);
            s2[r] += __shfl_xor(s2[r], m);
        }
    if (c == 0) {
#pragma unroll
        for (int r = 0; r < 4; ++r) {
            stats[h][0][r0 + r] = s1[r];
            stats[h][1][r0 + r] = s2[r];
        }
    }
    __syncthreads();
    float mean[4], inv[4];
#pragma unroll
    for (int r = 0; r < 4; ++r) {
        float t1 = stats[0][0][r0 + r] + stats[1][0][r0 + r];
        float t2 = stats[0][1][r0 + r] + stats[1][1][r0 + r];
        mean[r] = t1 * (1.0f / 256.0f);
        float var = t2 * (1.0f / 256.0f) - mean[r] * mean[r];
        inv[r] = rsqrtf(var + 1e-5f);
    }

    // per-wave LDS transpose -> full-line f32x2 stores
    f32x2 g2 = *reinterpret_cast<const f32x2*>(ln_g + 128 * h + 2 * lane);
    f32x2 b2 = *reinterpret_cast<const f32x2*>(ln_b + 128 * h + 2 * lane);
    float* ob = out + ((size_t)(a * BB + b)) * SS * HH + 128 * h;
#pragma unroll
    for (int r = 0; r < 4; ++r) {
#pragma unroll
        for (int n = 0; n < 8; ++n)
            etile[wave][g][n * 16 + c] = (acc[n][r] - mean[r]) * inv[r];
        // wave-private tile: in-wave LDS ordering (lgkmcnt), no barrier needed
#pragma unroll
        for (int t = 0; t < 4; ++t) {
            f32x2 x2 = *reinterpret_cast<const f32x2*>(&etile[wave][t][2 * lane]);
            *reinterpret_cast<f32x2*>(ob + (size_t)(16 * rt + 4 * t + r) * HH + 2 * lane) =
                x2 * g2 + b2;
        }
    }
}

// ---------------------------------------------------------------------------
extern "C" void kernel_launch(void* const* d_in, const int* in_sizes, int n_in,
                              void* d_out, int out_size, void* d_ws, size_t ws_size,
                              hipStream_t stream) {
    const float* Xa = (const float*)d_in[0];
    const float* Xb = (const float*)d_in[1];
    const float* Wq = (const float*)d_in[2];
    const float* bq = (const float*)d_in[3];
    const float* Wk = (const float*)d_in[4];
    const float* bk = (const float*)d_in[5];
    const float* Wv = (const float*)d_in[6];
    const float* bv = (const float*)d_in[7];
    const float* ln_g = (const float*)d_in[8];
    const float* ln_b = (const float*)d_in[9];
    float* out = (float*)d_out;

    char* ws = (char*)d_ws;
    short* wt    = (short*)(ws);               // 1,179,648 B
    float* q_ws  = (float*)(ws + 1179648);     // 4,718,592 B
    float* k_ws  = (float*)(ws + 5898240);     // 4,718,592 B (dead after norm)
    short* qn_ws = (short*)(ws + 10616832);    // 2,359,296 B
    short* kn_ws = (short*)(ws + 12976128);    // 2,359,296 B
    short* vt_ws = (short*)(ws + 15335424);    // 2,359,296 B (end 17,694,720)

    // T buffer: up to 48x48x96x96 bf16 = 42,467,328 B; chunk if ws is small.
    const size_t t_full = (size_t)BA * BB * SS * SS * 2;
    size_t t_off = 17694720;
    size_t avail = (ws_size > t_off) ? ws_size - t_off : 0;
    int nch;
    if (avail >= t_full) nch = 1;
    else if (avail >= t_full / 2) nch = 2;
    else if (avail >= t_full / 4) nch = 4;
    else if (avail >= t_full / 8) nch = 8;
    else { nch = 16; t_off = 5898240; }  // overlay dead k_ws (needs 2.66 MB)
    short* t_ws = (short*)(ws + t_off);
    int apc = BA / nch;

    wt_kernel<<<dim3(12, 4, 3), dim3(256), 0, stream>>>(Wq, Wk, Wv, wt);
    qkv_kernel<<<dim3(BA, 3, 4), dim3(384), 0, stream>>>(Xa, Xb, bq, bk, bv, wt,
                                                         q_ws, k_ws, vt_ws);
    norm_kernel<<<dim3(2304), dim3(256), 0, stream>>>(q_ws, k_ws, qn_ws, kn_ws);
    for (int ch = 0; ch < nch; ++ch) {
        sink_kernel<<<dim3(12, apc), dim3(256), 0, stream>>>(qn_ws, kn_ws, t_ws, ch * apc);
        pv_kernel<<<dim3(BB, apc), dim3(768), 0, stream>>>(t_ws, vt_ws, q_ws,
                                                           ln_g, ln_b, out, ch * apc);
    }
}